// Round 12
// baseline (1671.234 us; speedup 1.0000x reference)
//
#include <hip/hip_runtime.h>
#include <stdint.h>

#define NB 512
#define NT 64
#define NF 128
#define NU 1024
#define NG 4096
#define NS 32

typedef __attribute__((ext_vector_type(8))) short short8;
typedef __attribute__((ext_vector_type(4))) float f32x4;
typedef __attribute__((ext_vector_type(4))) unsigned int u32x4;

__device__ __forceinline__ float sigm(float x) { return 1.0f / (1.0f + __expf(-x)); }
__device__ __forceinline__ float tanh_f(float x) {
  float ax = fabsf(x);
  float e = __expf(2.0f * ax);        // e >= 1; inf ok
  float t = 1.0f - 2.0f / (e + 1.0f);
  return copysignf(t, x);
}
__device__ __forceinline__ unsigned short f2bf(float f) {
  union { float f; unsigned u; } v; v.f = f;
  unsigned r = v.u + 0x7fffu + ((v.u >> 16) & 1u);  // RNE
  return (unsigned short)(r >> 16);
}
__device__ __forceinline__ short8 as_s8(u32x4 v) { return __builtin_bit_cast(short8, v); }

// R3-proven h-exchange: write-through (sc0 sc1) stores land in the memory-side
// L3; consumers read with sc0 sc1 bypass loads. No fences, no L2 maintenance.
// LESSONS: (R4) per-step RELEASE fences blow FETCH up 6.5x. (R5/R6/R10/R11)
// register state above the VGPR cap silently spills to scratch: FETCH explodes
// (spill reloaded every consumer iteration), both pipes idle. VGPR_Count
// pinned at 128 came from __launch_bounds__(512,2) (2nd arg = min BLOCKS/CU,
// CUDA semantics: 16 waves/CU -> cap 128). LDS pins 1 block/CU anyway, so
// (512,1) frees the cap to 256 at identical occupancy. (R9) group barrier.
__device__ __forceinline__ void coh_store_bf16(unsigned short* p, unsigned v) {
  asm volatile("global_store_short %0, %1, off sc0 sc1" :: "v"(p), "v"(v) : "memory");
}

// ---------------- one fused LSTM step ----------------
// Tile: 32 rows x 64 units x 4 gates. 8 waves = kh(2 K-halves) x wu(4).
// Barrier split: arrive at step end, wait at step head; the 4-deep B prefetch
// (plain loads, 64 VGPRs — now affordable under the 256 cap) is issued BEFORE
// the wait so the L2 B-stream overlaps barrier skew + staging latency.
template <int KX>
__device__ __forceinline__ void do_step(
    const unsigned short* __restrict__ hIn,   // [512][1024] bf16 (read via sc0 sc1)
    const unsigned short* __restrict__ Bp,    // packed [128][4096][8] bf16
    const unsigned short* __restrict__ Xp,    // [64][512][128] bf16 or null
    const unsigned short* __restrict__ W1p,   // packed [16][4096][8] bf16 or null
    int tstep, f32x4 bA, f32x4 (&cst)[2],
    unsigned short* __restrict__ hOut, unsigned short* __restrict__ hOut2,
    unsigned short* lds,
    unsigned* gf, int u_blk, unsigned gen,    // group-barrier state
    int r0, int u0, int kh, int wu, int lr, int g4, int ucol, int tid)
{
  constexpr int ROWE = NU + KX;
  const int kcb = kh * 16;

  // ---- (1) 4-deep B prefetch, BEFORE the wait: weights are read-only ----
  u32x4 nb[4][4];
#pragma unroll
  for (int p = 0; p < 4; ++p) {
    size_t base = ((size_t)((kcb + p) * 4 + g4) * NG + ucol) * 8;
#pragma unroll
    for (int g = 0; g < 4; ++g)
      nb[p][g] = *(const u32x4*)(Bp + base + (size_t)g * NU * 8);
  }
  __builtin_amdgcn_sched_barrier(0);   // pin prefetch issue before the spin

  // ---- (2) WAIT: group peers' h of the previous step (flags >= gen) ----
  if (threadIdx.x < 16) {
    while (__hip_atomic_load(gf + threadIdx.x, __ATOMIC_RELAXED, __HIP_MEMORY_SCOPE_AGENT) < gen)
      __builtin_amdgcn_s_sleep(1);
  }
  __syncthreads();

  // ---- (3) stage A (h rows) into LDS, XOR-swizzled (R3 verbatim) ----
  {
    u32x4 t[8];
    const unsigned short* src[8];
    int loff[8];
#pragma unroll
    for (int it = 0; it < 8; ++it) {
      int i = tid + it * 512;
      int r = i >> 7, cb = i & 127;
      src[it] = hIn + (size_t)(r0 + r) * NU + cb * 8;
      loff[it] = r * (ROWE * 2) + ((cb * 16) ^ ((r & 7) << 4));
    }
#pragma unroll
    for (int it = 0; it < 8; ++it)
      asm volatile("global_load_dwordx4 %0, %1, off sc0 sc1" : "=v"(t[it]) : "v"(src[it]));
    if constexpr (KX > 0) {
      int r = tid >> 4, cb = tid & 15;            // 32 rows x 16 chunks = 512
      u32x4 vx = *(const u32x4*)(Xp + ((size_t)tstep * NB + (r0 + r)) * NF + cb * 8);
      int ox = r * (ROWE * 2) + ((NU * 2 + cb * 16) ^ ((r & 7) << 4));
      asm volatile("s_waitcnt vmcnt(0)" ::: "memory");
      __builtin_amdgcn_sched_barrier(0);
#pragma unroll
      for (int it = 0; it < 8; ++it) *(u32x4*)((char*)lds + loff[it]) = t[it];
      *(u32x4*)((char*)lds + ox) = vx;
    } else {
      asm volatile("s_waitcnt vmcnt(0)" ::: "memory");
      __builtin_amdgcn_sched_barrier(0);
#pragma unroll
      for (int it = 0; it < 8; ++it) *(u32x4*)((char*)lds + loff[it]) = t[it];
    }
  }
  __syncthreads();

  f32x4 acc[4][2];
#pragma unroll
  for (int g = 0; g < 4; ++g)
#pragma unroll
    for (int rt = 0; rt < 2; ++rt) acc[g][rt] = (f32x4){0.f, 0.f, 0.f, 0.f};

  const char* ldsb = (const char*)lds;
  const int arow0 = lr * (ROWE * 2);
  const int arow1 = (16 + lr) * (ROWE * 2);
  const int axor = (lr & 7) << 4;

  // ---- (4) kc loop: 4-slot ring, kc&3 static under unroll-4, refill@+4 ----
#pragma unroll 4
  for (int kc = 0; kc < 16; ++kc) {
    short8 bb[4];
#pragma unroll
    for (int g = 0; g < 4; ++g) bb[g] = as_s8(nb[kc & 3][g]);
    if (kc < 12) {
      size_t base = ((size_t)((kcb + kc + 4) * 4 + g4) * NG + ucol) * 8;
#pragma unroll
      for (int g = 0; g < 4; ++g)
        nb[kc & 3][g] = *(const u32x4*)(Bp + base + (size_t)g * NU * 8);
    }
    int kb = ((kcb + kc) * 64 + g4 * 16) ^ axor;
    short8 a0 = *(const short8*)(ldsb + arow0 + kb);
    short8 a1 = *(const short8*)(ldsb + arow1 + kb);
#pragma unroll
    for (int g = 0; g < 4; ++g) {
      acc[g][0] = __builtin_amdgcn_mfma_f32_16x16x32_bf16(a0, bb[g], acc[g][0], 0, 0, 0);
      acc[g][1] = __builtin_amdgcn_mfma_f32_16x16x32_bf16(a1, bb[g], acc[g][1], 0, 0, 0);
    }
  }
  if constexpr (KX > 0) {
#pragma unroll
    for (int kc = kh * 2; kc < kh * 2 + 2; ++kc) {
      int kb = (NU * 2 + kc * 64 + g4 * 16) ^ axor;
      short8 a0 = *(const short8*)(ldsb + arow0 + kb);
      short8 a1 = *(const short8*)(ldsb + arow1 + kb);
      size_t base = ((size_t)(kc * 4 + g4) * NG + ucol) * 8;
      short8 bb[4];
#pragma unroll
      for (int g = 0; g < 4; ++g) bb[g] = *(const short8*)(W1p + base + (size_t)g * NU * 8);
#pragma unroll
      for (int g = 0; g < 4; ++g) {
        acc[g][0] = __builtin_amdgcn_mfma_f32_16x16x32_bf16(a0, bb[g], acc[g][0], 0, 0, 0);
        acc[g][1] = __builtin_amdgcn_mfma_f32_16x16x32_bf16(a1, bb[g], acc[g][1], 0, 0, 0);
      }
    }
  }

  // ---- (5) K-split reduction via LDS (A-region reused; R3 verbatim) ----
  __syncthreads();
  float* red = (float*)lds;
  const int l = (g4 << 4) | lr;
  if (kh == 1) {
#pragma unroll
    for (int g = 0; g < 4; ++g)
#pragma unroll
      for (int rt = 0; rt < 2; ++rt)
        *(f32x4*)(red + (size_t)(((wu * 8) + (g * 2 + rt)) * 64 + l) * 4) = acc[g][rt];
  }
  __syncthreads();
  if (kh == 0) {
#pragma unroll
    for (int g = 0; g < 4; ++g)
#pragma unroll
      for (int rt = 0; rt < 2; ++rt)
        acc[g][rt] += *(const f32x4*)(red + (size_t)(((wu * 8) + (g * 2 + rt)) * 64 + l) * 4);

    // ---- epilogue: gates + c update in registers, h via coherent stores ----
#pragma unroll
    for (int rt = 0; rt < 2; ++rt) {
#pragma unroll
      for (int j = 0; j < 4; ++j) {
        int r = r0 + rt * 16 + g4 * 4 + j;   // C/D: row=(lane>>4)*4+j, col=lane&15
        size_t idx = (size_t)r * NU + ucol;
        float iv = sigm(acc[0][rt][j] + bA[0]);
        float fv = sigm(acc[1][rt][j] + bA[1]);
        float gv = tanh_f(acc[2][rt][j] + bA[2]);
        float ov = sigm(acc[3][rt][j] + bA[3]);
        float cN = fv * cst[rt][j] + iv * gv;
        cst[rt][j] = cN;
        unsigned hv = f2bf(ov * tanh_f(cN));
        coh_store_bf16(hOut + idx, hv);
        if (hOut2) coh_store_bf16(hOut2 + idx, hv);
      }
    }
  }

  // ---- (6) ARRIVE: __syncthreads drains vmcnt (h stores visible), post flag ----
  __syncthreads();
  if (threadIdx.x == 0)
    __hip_atomic_store(gf + u_blk, gen + 1, __ATOMIC_RELAXED, __HIP_MEMORY_SCOPE_AGENT);
}

// ---------------- persistent kernel: whole 126-step serial chain ----------------
// (512,1): 1 block/CU min -> VGPR cap 256. Occupancy is LDS-pinned at 1
// block/CU regardless, so the extra registers are free.
__global__ __launch_bounds__(512, 1) void lstm_seq(
    const unsigned short* __restrict__ U1p, const unsigned short* __restrict__ U1pp,
    const unsigned short* __restrict__ W2U2p, const unsigned short* __restrict__ W1p,
    const unsigned short* __restrict__ x2,
    const float* __restrict__ b1, const float* __restrict__ b1p, const float* __restrict__ b2,
    unsigned short* __restrict__ h0, unsigned short* __restrict__ h1,
    unsigned short* __restrict__ hist, unsigned* __restrict__ flags)
{
  extern __shared__ unsigned short lds[];
  const int bid = blockIdx.x;
  const int xcd = bid & 7, slot = bid >> 3;     // XCD-aware: per-XCD B slice ~1MB, L2-resident
  const int u_blk = xcd * 2 + (slot >> 4);
  const int m_blk = slot & 15;
  const int r0 = m_blk * 32, u0 = u_blk * 64;
  const int tid = threadIdx.x;
  const int w = tid >> 6, kh = w >> 2, wu = w & 3;
  const int lr = tid & 15, g4 = (tid >> 4) & 3;
  const int ucol = u0 + wu * 16 + lr;
  const size_t HS = (size_t)NB * NU;
  unsigned* gf = flags + m_blk * 64;            // this group's flag line

  f32x4 bW, bC1, bC2;
#pragma unroll
  for (int g = 0; g < 4; ++g) {
    bW[g]  = b1 [g * NU + ucol];
    bC1[g] = b1p[g * NU + ucol];
    bC2[g] = b2 [g * NU + ucol];
  }
  f32x4 cst[2];
  cst[0] = (f32x4){0.f, 0.f, 0.f, 0.f};
  cst[1] = (f32x4){0.f, 0.f, 0.f, 0.f};

  unsigned gen = 0;
  // warmup: h0 (zeroed) <-> h1; final h lands in h0-slot (also hist[0])
  for (int t = 0; t < NT; ++t) {
    const unsigned short* hi = (t & 1) ? h1 : h0;
    unsigned short* ho = (t & 1) ? h0 : h1;
    do_step<NF>(hi, U1p, x2, W1p, t, bW, cst, ho, (t == NT - 1) ? hist : nullptr,
                lds, gf, u_blk, gen, r0, u0, kh, wu, lr, g4, ucol, tid);
    ++gen;
  }
  // AR: cell1 (U1'=Wd@W1+U1): h0->h1 ; cell2 (W2+U2): h1->h0 (+hist[s+1])
  for (int s = 0; s < NS - 1; ++s) {
    do_step<0>(h0, U1pp, nullptr, nullptr, 0, bC1, cst, h1, nullptr,
               lds, gf, u_blk, gen, r0, u0, kh, wu, lr, g4, ucol, tid);
    ++gen;
    do_step<0>(h1, W2U2p, nullptr, nullptr, 0, bC2, cst, h0, hist + (size_t)(s + 1) * HS,
               lds, gf, u_blk, gen, r0, u0, kh, wu, lr, g4, ucol, tid);
    ++gen;
  }
}

// ---------------- batched output projection: out[b][s][f] = hist[s][b]@Wd + bd ----------------
__global__ __launch_bounds__(256, 2) void pred_gemm(
    const unsigned short* __restrict__ H,    // [32*512][1024] bf16
    const unsigned short* __restrict__ Wdp,  // packed [128][128][8] bf16
    const float* __restrict__ bd, float* __restrict__ out)
{
  __shared__ unsigned short lds[32 * NU];
  const int tid = threadIdx.x;
  const int r0 = blockIdx.x * 32;
  for (int i = tid; i < 32 * 128; i += 256) {
    int r = i >> 7, cb = i & 127;
    uint4 v = *(const uint4*)(H + (size_t)(r0 + r) * NU + cb * 8);
    int off = r * 2048 + ((cb * 16) ^ ((r & 7) << 4));
    *(uint4*)((char*)lds + off) = v;
  }
  __syncthreads();
  const int w = tid >> 6, l = tid & 63, lr = l & 15, g4 = l >> 4;
  f32x4 acc[2][2];
#pragma unroll
  for (int a = 0; a < 2; ++a)
#pragma unroll
    for (int c = 0; c < 2; ++c) acc[a][c] = (f32x4){0.f, 0.f, 0.f, 0.f};
  const char* ldsb = (const char*)lds;
  const int arow0 = lr * 2048, arow1 = (16 + lr) * 2048, axor = (lr & 7) << 4;
  const int col0 = w * 32 + lr;
#pragma unroll 4
  for (int kc = 0; kc < 32; ++kc) {
    int kb = (kc * 64 + g4 * 16) ^ axor;
    short8 a0 = *(const short8*)(ldsb + arow0 + kb);
    short8 a1 = *(const short8*)(ldsb + arow1 + kb);
    size_t base = ((size_t)(kc * 4 + g4) * NF) * 8;
    short8 w0 = *(const short8*)(Wdp + base + (size_t)col0 * 8);
    short8 w1 = *(const short8*)(Wdp + base + (size_t)(col0 + 16) * 8);
    acc[0][0] = __builtin_amdgcn_mfma_f32_16x16x32_bf16(a0, w0, acc[0][0], 0, 0, 0);
    acc[1][0] = __builtin_amdgcn_mfma_f32_16x16x32_bf16(a1, w0, acc[1][0], 0, 0, 0);
    acc[0][1] = __builtin_amdgcn_mfma_f32_16x16x32_bf16(a0, w1, acc[0][1], 0, 0, 0);
    acc[1][1] = __builtin_amdgcn_mfma_f32_16x16x32_bf16(a1, w1, acc[1][1], 0, 0, 0);
  }
#pragma unroll
  for (int rt = 0; rt < 2; ++rt)
#pragma unroll
    for (int ct = 0; ct < 2; ++ct)
#pragma unroll
      for (int j = 0; j < 4; ++j) {
        int r = r0 + rt * 16 + g4 * 4 + j;
        int s = r >> 9, bb = r & 511;
        int f = w * 32 + ct * 16 + lr;
        out[((size_t)bb * NS + s) * NF + f] = acc[rt][ct][j] + bd[f];
      }
}

// ---------------- prep kernels ----------------
// x2 in [T][B][F] layout (contiguous per-step staging)
__global__ void prep_x(const float* __restrict__ in, const float* __restrict__ mean,
                       const float* __restrict__ var, unsigned short* __restrict__ x2) {
  int i = (blockIdx.x * 256 + threadIdx.x) * 4;
  int f = i & 127;
  int bt = i >> 7;
  int b = bt >> 6, t = bt & 63;
  float4 v = *(const float4*)(in + i);
  float vv[4] = {v.x, v.y, v.z, v.w};
  unsigned short o[4] __attribute__((aligned(8)));
#pragma unroll
  for (int j = 0; j < 4; ++j) {
    float inv = rsqrtf(var[f + j] + 1e-7f);
    float s = inv * inv;
    float m2 = mean[f + j] * (s + inv);   // double-normalization folded
    o[j] = f2bf(vv[j] * s - m2);
  }
  *(uint2*)(x2 + (((size_t)t * NB + b) << 7) + f) = *(const uint2*)o;
}

// P[(k/8)*N*8 + c*8 + k%8] = bf16(A[k][c] (+ A2[k][c]))
__global__ void prep_pack(const float* __restrict__ A, const float* __restrict__ A2,
                          unsigned short* __restrict__ P, int N) {
  int idx = blockIdx.x * 256 + threadIdx.x;
  int kg = idx / N, c = idx - kg * N;
  unsigned short o[8] __attribute__((aligned(16)));
#pragma unroll
  for (int j = 0; j < 8; ++j) {
    size_t e = (size_t)(kg * 8 + j) * N + c;
    float vv = A[e];
    if (A2) vv += A2[e];
    o[j] = f2bf(vv);
  }
  *(uint4*)(P + (size_t)idx * 8) = *(const uint4*)o;
}

// U1' = U1 + Wd@W1, packed.  Wd slice staged in LDS; m-loop unrolled.
__global__ __launch_bounds__(256) void prep_u1pp(
    const float* __restrict__ U1, const float* __restrict__ Wd,
    const float* __restrict__ W1, unsigned short* __restrict__ P) {
  __shared__ float wd[8][NF];
  const int kg = blockIdx.x >> 4;
  const int c = ((blockIdx.x & 15) << 8) + threadIdx.x;
  for (int i = threadIdx.x; i < 8 * NF; i += 256)
    wd[i >> 7][i & 127] = Wd[(size_t)(kg * 8 + (i >> 7)) * NF + (i & 127)];
  __syncthreads();
  float a[8];
#pragma unroll
  for (int j = 0; j < 8; ++j) a[j] = U1[(size_t)(kg * 8 + j) * NG + c];
#pragma unroll 8
  for (int m = 0; m < NF; ++m) {
    float w1v = W1[(size_t)m * NG + c];
#pragma unroll
    for (int j = 0; j < 8; ++j) a[j] += wd[j][m] * w1v;
  }
  unsigned short o[8] __attribute__((aligned(16)));
#pragma unroll
  for (int j = 0; j < 8; ++j) o[j] = f2bf(a[j]);
  *(uint4*)(P + (size_t)(kg * NG + c) * 8) = *(const uint4*)o;
}

__global__ void prep_wdp(const float* __restrict__ Wd, unsigned short* __restrict__ P) {
  int idx = blockIdx.x * 256 + threadIdx.x;  // kg*128 + f
  int kg = idx >> 7, f = idx & 127;
  unsigned short o[8] __attribute__((aligned(16)));
#pragma unroll
  for (int j = 0; j < 8; ++j) o[j] = f2bf(Wd[(size_t)(kg * 8 + j) * NF + f]);
  *(uint4*)(P + (size_t)idx * 8) = *(const uint4*)o;
}

// b1' = b1 + bd@W1
__global__ void prep_b1p(const float* __restrict__ b1, const float* __restrict__ bd,
                         const float* __restrict__ W1, float* __restrict__ o) {
  int c = blockIdx.x * 256 + threadIdx.x;
  float acc = b1[c];
#pragma unroll 8
  for (int m = 0; m < NF; ++m) acc += bd[m] * W1[(size_t)m * NG + c];
  o[c] = acc;
}

extern "C" void kernel_launch(void* const* d_in, const int* in_sizes, int n_in,
                              void* d_out, int out_size, void* d_ws, size_t ws_size,
                              hipStream_t stream) {
  const float* inputs = (const float*)d_in[0];
  const float* mean = (const float*)d_in[1];
  const float* var  = (const float*)d_in[2];
  const float* W1   = (const float*)d_in[3];
  const float* U1   = (const float*)d_in[4];
  const float* b1   = (const float*)d_in[5];
  const float* W2   = (const float*)d_in[6];
  const float* U2   = (const float*)d_in[7];
  const float* b2   = (const float*)d_in[8];
  const float* Wd   = (const float*)d_in[9];
  const float* bd   = (const float*)d_in[10];
  float* out = (float*)d_out;
  char* ws = (char*)d_ws;

  size_t off = 0;
  auto alloc = [&](size_t bytes) { char* p = ws + off; off += (bytes + 255) & ~255ull; return p; };
  unsigned short* h0    = (unsigned short*)alloc((size_t)NB * NU * 2);
  unsigned short* h1    = (unsigned short*)alloc((size_t)NB * NU * 2);
  unsigned short* hist  = (unsigned short*)alloc((size_t)NS * NB * NU * 2);
  unsigned short* x2    = (unsigned short*)alloc((size_t)NB * NT * NF * 2);
  unsigned short* U1p   = (unsigned short*)alloc((size_t)NU * NG * 2);
  unsigned short* U1pp  = (unsigned short*)alloc((size_t)NU * NG * 2);
  unsigned short* W2U2p = (unsigned short*)alloc((size_t)NU * NG * 2);
  unsigned short* W1p   = (unsigned short*)alloc((size_t)NF * NG * 2);
  unsigned short* Wdp   = (unsigned short*)alloc((size_t)NU * NF * 2);
  float* b1p            = (float*)alloc((size_t)NG * 4);
  unsigned* flags       = (unsigned*)alloc(16 * 64 * 4);   // 16 groups x 64-word line

  hipMemsetAsync(h0, 0, (size_t)NB * NU * 2, stream);
  hipMemsetAsync(flags, 0, 16 * 64 * 4, stream);

  prep_x   <<<(NB * NT * NF) / 1024, 256, 0, stream>>>(inputs, mean, var, x2);
  prep_pack<<<(NU / 8) * NG / 256, 256, 0, stream>>>(U1, nullptr, U1p, NG);
  prep_u1pp<<<(NU / 8) * NG / 256, 256, 0, stream>>>(U1, Wd, W1, U1pp);
  prep_pack<<<(NU / 8) * NG / 256, 256, 0, stream>>>(W2, U2, W2U2p, NG);
  prep_pack<<<(NF / 8) * NG / 256, 256, 0, stream>>>(W1, nullptr, W1p, NG);
  prep_wdp <<<(NU / 8) * NF / 256, 256, 0, stream>>>(Wd, Wdp);
  prep_b1p <<<NG / 256, 256, 0, stream>>>(b1, bd, W1, b1p);

  // whole serial chain in one persistent kernel (R9 structure; 4-deep B
  // prefetch before the wait; launch_bounds(512,1) frees VGPR cap to 256).
  // 96KB LDS request -> 1 block/CU -> all 256 blocks co-resident.
  lstm_seq<<<256, 512, 98304, stream>>>(U1p, U1pp, W2U2p, W1p, x2,
                                        b1, b1p, b2, h0, h1, hist, flags);

  // all 32 output projections in one parallel GEMM
  pred_gemm<<<(NS * NB) / 32, 256, 0, stream>>>(hist, Wdp, bd, out);
}

// Round 13
// 1188.251 us; speedup vs baseline: 1.4065x; 1.4065x over previous
//
#include <hip/hip_runtime.h>
#include <stdint.h>

#define NB 512
#define NT 64
#define NF 128
#define NU 1024
#define NG 4096
#define NS 32

typedef __attribute__((ext_vector_type(8))) short short8;
typedef __attribute__((ext_vector_type(4))) float f32x4;
typedef __attribute__((ext_vector_type(4))) unsigned int u32x4;

__device__ __forceinline__ float sigm(float x) { return 1.0f / (1.0f + __expf(-x)); }
__device__ __forceinline__ float tanh_f(float x) {
  float ax = fabsf(x);
  float e = __expf(2.0f * ax);        // e >= 1; inf ok
  float t = 1.0f - 2.0f / (e + 1.0f);
  return copysignf(t, x);
}
__device__ __forceinline__ unsigned short f2bf(float f) {
  union { float f; unsigned u; } v; v.f = f;
  unsigned r = v.u + 0x7fffu + ((v.u >> 16) & 1u);  // RNE
  return (unsigned short)(r >> 16);
}

// R3-proven h-exchange: write-through (sc0 sc1) stores land in the memory-side
// L3; consumers read with sc0 sc1 bypass loads. No fences, no L2 maintenance.
// SESSION LESSONS (final): (R4) per-step RELEASE fences blow FETCH up 6.5x.
// (R5/R6/R10/R11/R12) this kernel's VGPR envelope is HARD-CAPPED at 128 by the
// compiler (launch_bounds(512,1) did not lift it) — any added register state
// (64-row tile acc[4][4], 4/6-deep B prefetch rings) silently spills to
// scratch: FETCH +0.8-4 GB, pipes idle. R9's structure is register-full and
// is the optimum of this design. (R7/R8) bundled step-rewrites doubled FETCH.
// (R9) 16-block group barrier instead of grid barrier: -200us.
__device__ __forceinline__ void coh_store_bf16(unsigned short* p, unsigned v) {
  asm volatile("global_store_short %0, %1, off sc0 sc1" :: "v"(p), "v"(v) : "memory");
}

// ---- 16-block GROUP barrier ----
// Block (m,u) only consumes h rows written by the 16 blocks sharing m_blk,
// and c/x2/hist accesses are group-local -> no global barrier needed.
// Each group has its own 64-word flag line region: gf = flags + m_blk*64.
__device__ __forceinline__ void gbar_grp(unsigned* gf, int u_blk, unsigned gen) {
  __syncthreads();   // compiler drains vmcnt -> write-through h stores visible
  if (threadIdx.x == 0)
    __hip_atomic_store(gf + u_blk, gen, __ATOMIC_RELAXED, __HIP_MEMORY_SCOPE_AGENT);
  if (threadIdx.x < 16) {
    while (__hip_atomic_load(gf + threadIdx.x, __ATOMIC_RELAXED, __HIP_MEMORY_SCOPE_AGENT) < gen)
      __builtin_amdgcn_s_sleep(1);
  }
  __syncthreads();
}

// ---------------- one fused LSTM step (R3 core, proven) ----------------
// Tile: 32 rows x 64 units x 4 gates. 8 waves = kh(2 K-halves) x wu(4).
// K-split partials reduced through LDS; epilogue on kh==0 waves.
template <int KX>
__device__ __forceinline__ void do_step(
    const unsigned short* __restrict__ hIn,   // [512][1024] bf16 (read via sc0 sc1)
    const unsigned short* __restrict__ Bp,    // packed [128][4096][8] bf16
    const unsigned short* __restrict__ Xp,    // [64][512][128] bf16 or null
    const unsigned short* __restrict__ W1p,   // packed [16][4096][8] bf16 or null
    int tstep, f32x4 bA, f32x4 (&cst)[2],
    unsigned short* __restrict__ hOut, unsigned short* __restrict__ hOut2,
    unsigned short* lds,
    int r0, int u0, int kh, int wu, int lr, int g4, int ucol, int tid)
{
  constexpr int ROWE = NU + KX;

  // ---- stage A (h rows) into LDS, XOR-swizzled; coherent loads bypass L1/L2 ----
  {
    u32x4 t[8];
    const unsigned short* src[8];
    int loff[8];
#pragma unroll
    for (int it = 0; it < 8; ++it) {
      int i = tid + it * 512;
      int r = i >> 7, cb = i & 127;
      src[it] = hIn + (size_t)(r0 + r) * NU + cb * 8;
      loff[it] = r * (ROWE * 2) + ((cb * 16) ^ ((r & 7) << 4));
    }
#pragma unroll
    for (int it = 0; it < 8; ++it)
      asm volatile("global_load_dwordx4 %0, %1, off sc0 sc1" : "=v"(t[it]) : "v"(src[it]));
    if constexpr (KX > 0) {
      int r = tid >> 4, cb = tid & 15;            // 32 rows x 16 chunks = 512
      u32x4 vx = *(const u32x4*)(Xp + ((size_t)tstep * NB + (r0 + r)) * NF + cb * 8);
      int ox = r * (ROWE * 2) + ((NU * 2 + cb * 16) ^ ((r & 7) << 4));
      asm volatile("s_waitcnt vmcnt(0)" ::: "memory");
      __builtin_amdgcn_sched_barrier(0);
#pragma unroll
      for (int it = 0; it < 8; ++it) *(u32x4*)((char*)lds + loff[it]) = t[it];
      *(u32x4*)((char*)lds + ox) = vx;
    } else {
      asm volatile("s_waitcnt vmcnt(0)" ::: "memory");
      __builtin_amdgcn_sched_barrier(0);
#pragma unroll
      for (int it = 0; it < 8; ++it) *(u32x4*)((char*)lds + loff[it]) = t[it];
    }
  }
  __syncthreads();

  f32x4 acc[4][2];
#pragma unroll
  for (int g = 0; g < 4; ++g)
#pragma unroll
    for (int rt = 0; rt < 2; ++rt) acc[g][rt] = (f32x4){0.f, 0.f, 0.f, 0.f};

  const char* ldsb = (const char*)lds;
  const int arow0 = lr * (ROWE * 2);
  const int arow1 = (16 + lr) * (ROWE * 2);
  const int axor = (lr & 7) << 4;
  const int kcb = kh * 16;

  // 2-deep B prefetch (register-budget-proven; do NOT deepen — spills)
  short8 nb[2][4];
  {
    size_t b0 = ((size_t)(kcb * 4 + g4) * NG + ucol) * 8;
    size_t b1 = ((size_t)((kcb + 1) * 4 + g4) * NG + ucol) * 8;
#pragma unroll
    for (int g = 0; g < 4; ++g) {
      nb[0][g] = *(const short8*)(Bp + b0 + (size_t)g * NU * 8);
      nb[1][g] = *(const short8*)(Bp + b1 + (size_t)g * NU * 8);
    }
  }
#pragma unroll 4
  for (int kc = 0; kc < 16; ++kc) {
    short8 bb[4];
#pragma unroll
    for (int g = 0; g < 4; ++g) bb[g] = nb[kc & 1][g];
    if (kc < 14) {
      size_t base = ((size_t)((kcb + kc + 2) * 4 + g4) * NG + ucol) * 8;
#pragma unroll
      for (int g = 0; g < 4; ++g) nb[kc & 1][g] = *(const short8*)(Bp + base + (size_t)g * NU * 8);
    }
    int kb = ((kcb + kc) * 64 + g4 * 16) ^ axor;
    short8 a0 = *(const short8*)(ldsb + arow0 + kb);
    short8 a1 = *(const short8*)(ldsb + arow1 + kb);
#pragma unroll
    for (int g = 0; g < 4; ++g) {
      acc[g][0] = __builtin_amdgcn_mfma_f32_16x16x32_bf16(a0, bb[g], acc[g][0], 0, 0, 0);
      acc[g][1] = __builtin_amdgcn_mfma_f32_16x16x32_bf16(a1, bb[g], acc[g][1], 0, 0, 0);
    }
  }
  if constexpr (KX > 0) {
#pragma unroll
    for (int kc = kh * 2; kc < kh * 2 + 2; ++kc) {
      int kb = (NU * 2 + kc * 64 + g4 * 16) ^ axor;
      short8 a0 = *(const short8*)(ldsb + arow0 + kb);
      short8 a1 = *(const short8*)(ldsb + arow1 + kb);
      size_t base = ((size_t)(kc * 4 + g4) * NG + ucol) * 8;
      short8 bb[4];
#pragma unroll
      for (int g = 0; g < 4; ++g) bb[g] = *(const short8*)(W1p + base + (size_t)g * NU * 8);
#pragma unroll
      for (int g = 0; g < 4; ++g) {
        acc[g][0] = __builtin_amdgcn_mfma_f32_16x16x32_bf16(a0, bb[g], acc[g][0], 0, 0, 0);
        acc[g][1] = __builtin_amdgcn_mfma_f32_16x16x32_bf16(a1, bb[g], acc[g][1], 0, 0, 0);
      }
    }
  }

  // ---- K-split reduction via LDS (A-region reused) ----
  __syncthreads();
  float* red = (float*)lds;
  const int l = (g4 << 4) | lr;
  if (kh == 1) {
#pragma unroll
    for (int g = 0; g < 4; ++g)
#pragma unroll
      for (int rt = 0; rt < 2; ++rt)
        *(f32x4*)(red + (size_t)(((wu * 8) + (g * 2 + rt)) * 64 + l) * 4) = acc[g][rt];
  }
  __syncthreads();
  if (kh == 0) {
#pragma unroll
    for (int g = 0; g < 4; ++g)
#pragma unroll
      for (int rt = 0; rt < 2; ++rt)
        acc[g][rt] += *(const f32x4*)(red + (size_t)(((wu * 8) + (g * 2 + rt)) * 64 + l) * 4);

    // ---- epilogue: gates + c update in registers, h via coherent stores ----
#pragma unroll
    for (int rt = 0; rt < 2; ++rt) {
#pragma unroll
      for (int j = 0; j < 4; ++j) {
        int r = r0 + rt * 16 + g4 * 4 + j;   // C/D: row=(lane>>4)*4+j, col=lane&15
        size_t idx = (size_t)r * NU + ucol;
        float iv = sigm(acc[0][rt][j] + bA[0]);
        float fv = sigm(acc[1][rt][j] + bA[1]);
        float gv = tanh_f(acc[2][rt][j] + bA[2]);
        float ov = sigm(acc[3][rt][j] + bA[3]);
        float cN = fv * cst[rt][j] + iv * gv;
        cst[rt][j] = cN;
        unsigned hv = f2bf(ov * tanh_f(cN));
        coh_store_bf16(hOut + idx, hv);
        if (hOut2) coh_store_bf16(hOut2 + idx, hv);
      }
    }
  }
}

// ---------------- persistent kernel: whole 126-step serial chain ----------------
__global__ __launch_bounds__(512, 2) void lstm_seq(
    const unsigned short* __restrict__ U1p, const unsigned short* __restrict__ U1pp,
    const unsigned short* __restrict__ W2U2p, const unsigned short* __restrict__ W1p,
    const unsigned short* __restrict__ x2,
    const float* __restrict__ b1, const float* __restrict__ b1p, const float* __restrict__ b2,
    unsigned short* __restrict__ h0, unsigned short* __restrict__ h1,
    unsigned short* __restrict__ hist, unsigned* __restrict__ flags)
{
  extern __shared__ unsigned short lds[];
  const int bid = blockIdx.x;
  const int xcd = bid & 7, slot = bid >> 3;     // XCD-aware: per-XCD B slice ~1MB, L2-resident
  const int u_blk = xcd * 2 + (slot >> 4);
  const int m_blk = slot & 15;
  const int r0 = m_blk * 32, u0 = u_blk * 64;
  const int tid = threadIdx.x;
  const int w = tid >> 6, kh = w >> 2, wu = w & 3;
  const int lr = tid & 15, g4 = (tid >> 4) & 3;
  const int ucol = u0 + wu * 16 + lr;
  const size_t HS = (size_t)NB * NU;
  unsigned* gf = flags + m_blk * 64;            // this group's flag line

  f32x4 bW, bC1, bC2;
#pragma unroll
  for (int g = 0; g < 4; ++g) {
    bW[g]  = b1 [g * NU + ucol];
    bC1[g] = b1p[g * NU + ucol];
    bC2[g] = b2 [g * NU + ucol];
  }
  f32x4 cst[2];
  cst[0] = (f32x4){0.f, 0.f, 0.f, 0.f};
  cst[1] = (f32x4){0.f, 0.f, 0.f, 0.f};

  unsigned gen = 0;
  // warmup: h0 (zeroed) <-> h1; final h lands in h0-slot (also hist[0])
  for (int t = 0; t < NT; ++t) {
    const unsigned short* hi = (t & 1) ? h1 : h0;
    unsigned short* ho = (t & 1) ? h0 : h1;
    do_step<NF>(hi, U1p, x2, W1p, t, bW, cst, ho, (t == NT - 1) ? hist : nullptr,
                lds, r0, u0, kh, wu, lr, g4, ucol, tid);
    gbar_grp(gf, u_blk, ++gen);
  }
  // AR: cell1 (U1'=Wd@W1+U1): h0->h1 ; cell2 (W2+U2): h1->h0 (+hist[s+1])
  for (int s = 0; s < NS - 1; ++s) {
    do_step<0>(h0, U1pp, nullptr, nullptr, 0, bC1, cst, h1, nullptr,
               lds, r0, u0, kh, wu, lr, g4, ucol, tid);
    gbar_grp(gf, u_blk, ++gen);
    do_step<0>(h1, W2U2p, nullptr, nullptr, 0, bC2, cst, h0, hist + (size_t)(s + 1) * HS,
               lds, r0, u0, kh, wu, lr, g4, ucol, tid);
    gbar_grp(gf, u_blk, ++gen);
  }
}

// ---------------- batched output projection: out[b][s][f] = hist[s][b]@Wd + bd ----------------
__global__ __launch_bounds__(256, 2) void pred_gemm(
    const unsigned short* __restrict__ H,    // [32*512][1024] bf16
    const unsigned short* __restrict__ Wdp,  // packed [128][128][8] bf16
    const float* __restrict__ bd, float* __restrict__ out)
{
  __shared__ unsigned short lds[32 * NU];
  const int tid = threadIdx.x;
  const int r0 = blockIdx.x * 32;
  for (int i = tid; i < 32 * 128; i += 256) {
    int r = i >> 7, cb = i & 127;
    uint4 v = *(const uint4*)(H + (size_t)(r0 + r) * NU + cb * 8);
    int off = r * 2048 + ((cb * 16) ^ ((r & 7) << 4));
    *(uint4*)((char*)lds + off) = v;
  }
  __syncthreads();
  const int w = tid >> 6, l = tid & 63, lr = l & 15, g4 = l >> 4;
  f32x4 acc[2][2];
#pragma unroll
  for (int a = 0; a < 2; ++a)
#pragma unroll
    for (int c = 0; c < 2; ++c) acc[a][c] = (f32x4){0.f, 0.f, 0.f, 0.f};
  const char* ldsb = (const char*)lds;
  const int arow0 = lr * 2048, arow1 = (16 + lr) * 2048, axor = (lr & 7) << 4;
  const int col0 = w * 32 + lr;
#pragma unroll 4
  for (int kc = 0; kc < 32; ++kc) {
    int kb = (kc * 64 + g4 * 16) ^ axor;
    short8 a0 = *(const short8*)(ldsb + arow0 + kb);
    short8 a1 = *(const short8*)(ldsb + arow1 + kb);
    size_t base = ((size_t)(kc * 4 + g4) * NF) * 8;
    short8 w0 = *(const short8*)(Wdp + base + (size_t)col0 * 8);
    short8 w1 = *(const short8*)(Wdp + base + (size_t)(col0 + 16) * 8);
    acc[0][0] = __builtin_amdgcn_mfma_f32_16x16x32_bf16(a0, w0, acc[0][0], 0, 0, 0);
    acc[1][0] = __builtin_amdgcn_mfma_f32_16x16x32_bf16(a1, w0, acc[1][0], 0, 0, 0);
    acc[0][1] = __builtin_amdgcn_mfma_f32_16x16x32_bf16(a0, w1, acc[0][1], 0, 0, 0);
    acc[1][1] = __builtin_amdgcn_mfma_f32_16x16x32_bf16(a1, w1, acc[1][1], 0, 0, 0);
  }
#pragma unroll
  for (int rt = 0; rt < 2; ++rt)
#pragma unroll
    for (int ct = 0; ct < 2; ++ct)
#pragma unroll
      for (int j = 0; j < 4; ++j) {
        int r = r0 + rt * 16 + g4 * 4 + j;
        int s = r >> 9, bb = r & 511;
        int f = w * 32 + ct * 16 + lr;
        out[((size_t)bb * NS + s) * NF + f] = acc[rt][ct][j] + bd[f];
      }
}

// ---------------- prep kernels ----------------
// x2 in [T][B][F] layout (contiguous per-step staging)
__global__ void prep_x(const float* __restrict__ in, const float* __restrict__ mean,
                       const float* __restrict__ var, unsigned short* __restrict__ x2) {
  int i = (blockIdx.x * 256 + threadIdx.x) * 4;
  int f = i & 127;
  int bt = i >> 7;
  int b = bt >> 6, t = bt & 63;
  float4 v = *(const float4*)(in + i);
  float vv[4] = {v.x, v.y, v.z, v.w};
  unsigned short o[4] __attribute__((aligned(8)));
#pragma unroll
  for (int j = 0; j < 4; ++j) {
    float inv = rsqrtf(var[f + j] + 1e-7f);
    float s = inv * inv;
    float m2 = mean[f + j] * (s + inv);   // double-normalization folded
    o[j] = f2bf(vv[j] * s - m2);
  }
  *(uint2*)(x2 + (((size_t)t * NB + b) << 7) + f) = *(const uint2*)o;
}

// P[(k/8)*N*8 + c*8 + k%8] = bf16(A[k][c] (+ A2[k][c]))
__global__ void prep_pack(const float* __restrict__ A, const float* __restrict__ A2,
                          unsigned short* __restrict__ P, int N) {
  int idx = blockIdx.x * 256 + threadIdx.x;
  int kg = idx / N, c = idx - kg * N;
  unsigned short o[8] __attribute__((aligned(16)));
#pragma unroll
  for (int j = 0; j < 8; ++j) {
    size_t e = (size_t)(kg * 8 + j) * N + c;
    float vv = A[e];
    if (A2) vv += A2[e];
    o[j] = f2bf(vv);
  }
  *(uint4*)(P + (size_t)idx * 8) = *(const uint4*)o;
}

// U1' = U1 + Wd@W1, packed.  Wd slice staged in LDS; m-loop unrolled.
__global__ __launch_bounds__(256) void prep_u1pp(
    const float* __restrict__ U1, const float* __restrict__ Wd,
    const float* __restrict__ W1, unsigned short* __restrict__ P) {
  __shared__ float wd[8][NF];
  const int kg = blockIdx.x >> 4;
  const int c = ((blockIdx.x & 15) << 8) + threadIdx.x;
  for (int i = threadIdx.x; i < 8 * NF; i += 256)
    wd[i >> 7][i & 127] = Wd[(size_t)(kg * 8 + (i >> 7)) * NF + (i & 127)];
  __syncthreads();
  float a[8];
#pragma unroll
  for (int j = 0; j < 8; ++j) a[j] = U1[(size_t)(kg * 8 + j) * NG + c];
#pragma unroll 8
  for (int m = 0; m < NF; ++m) {
    float w1v = W1[(size_t)m * NG + c];
#pragma unroll
    for (int j = 0; j < 8; ++j) a[j] += wd[j][m] * w1v;
  }
  unsigned short o[8] __attribute__((aligned(16)));
#pragma unroll
  for (int j = 0; j < 8; ++j) o[j] = f2bf(a[j]);
  *(uint4*)(P + (size_t)(kg * NG + c) * 8) = *(const uint4*)o;
}

__global__ void prep_wdp(const float* __restrict__ Wd, unsigned short* __restrict__ P) {
  int idx = blockIdx.x * 256 + threadIdx.x;  // kg*128 + f
  int kg = idx >> 7, f = idx & 127;
  unsigned short o[8] __attribute__((aligned(16)));
#pragma unroll
  for (int j = 0; j < 8; ++j) o[j] = f2bf(Wd[(size_t)(kg * 8 + j) * NF + f]);
  *(uint4*)(P + (size_t)idx * 8) = *(const uint4*)o;
}

// b1' = b1 + bd@W1
__global__ void prep_b1p(const float* __restrict__ b1, const float* __restrict__ bd,
                         const float* __restrict__ W1, float* __restrict__ o) {
  int c = blockIdx.x * 256 + threadIdx.x;
  float acc = b1[c];
#pragma unroll 8
  for (int m = 0; m < NF; ++m) acc += bd[m] * W1[(size_t)m * NG + c];
  o[c] = acc;
}

extern "C" void kernel_launch(void* const* d_in, const int* in_sizes, int n_in,
                              void* d_out, int out_size, void* d_ws, size_t ws_size,
                              hipStream_t stream) {
  const float* inputs = (const float*)d_in[0];
  const float* mean = (const float*)d_in[1];
  const float* var  = (const float*)d_in[2];
  const float* W1   = (const float*)d_in[3];
  const float* U1   = (const float*)d_in[4];
  const float* b1   = (const float*)d_in[5];
  const float* W2   = (const float*)d_in[6];
  const float* U2   = (const float*)d_in[7];
  const float* b2   = (const float*)d_in[8];
  const float* Wd   = (const float*)d_in[9];
  const float* bd   = (const float*)d_in[10];
  float* out = (float*)d_out;
  char* ws = (char*)d_ws;

  size_t off = 0;
  auto alloc = [&](size_t bytes) { char* p = ws + off; off += (bytes + 255) & ~255ull; return p; };
  unsigned short* h0    = (unsigned short*)alloc((size_t)NB * NU * 2);
  unsigned short* h1    = (unsigned short*)alloc((size_t)NB * NU * 2);
  unsigned short* hist  = (unsigned short*)alloc((size_t)NS * NB * NU * 2);
  unsigned short* x2    = (unsigned short*)alloc((size_t)NB * NT * NF * 2);
  unsigned short* U1p   = (unsigned short*)alloc((size_t)NU * NG * 2);
  unsigned short* U1pp  = (unsigned short*)alloc((size_t)NU * NG * 2);
  unsigned short* W2U2p = (unsigned short*)alloc((size_t)NU * NG * 2);
  unsigned short* W1p   = (unsigned short*)alloc((size_t)NF * NG * 2);
  unsigned short* Wdp   = (unsigned short*)alloc((size_t)NU * NF * 2);
  float* b1p            = (float*)alloc((size_t)NG * 4);
  unsigned* flags       = (unsigned*)alloc(16 * 64 * 4);   // 16 groups x 64-word line

  hipMemsetAsync(h0, 0, (size_t)NB * NU * 2, stream);
  hipMemsetAsync(flags, 0, 16 * 64 * 4, stream);

  prep_x   <<<(NB * NT * NF) / 1024, 256, 0, stream>>>(inputs, mean, var, x2);
  prep_pack<<<(NU / 8) * NG / 256, 256, 0, stream>>>(U1, nullptr, U1p, NG);
  prep_u1pp<<<(NU / 8) * NG / 256, 256, 0, stream>>>(U1, Wd, W1, U1pp);
  prep_pack<<<(NU / 8) * NG / 256, 256, 0, stream>>>(W2, U2, W2U2p, NG);
  prep_pack<<<(NF / 8) * NG / 256, 256, 0, stream>>>(W1, nullptr, W1p, NG);
  prep_wdp <<<(NU / 8) * NF / 256, 256, 0, stream>>>(Wd, Wdp);
  prep_b1p <<<NG / 256, 256, 0, stream>>>(b1, bd, W1, b1p);

  // whole serial chain in one persistent kernel (R9 configuration — the
  // session's verified best: 1208us, FETCH 565MB, MfmaUtil 20%).
  // 96KB LDS request -> 1 block/CU -> all 256 blocks co-resident; barrier is
  // per-16-block row-group (the only true data dependency).
  lstm_seq<<<256, 512, 98304, stream>>>(U1p, U1pp, W2U2p, W1p, x2,
                                        b1, b1p, b2, h0, h1, hist, flags);

  // all 32 output projections in one parallel GEMM
  pred_gemm<<<(NS * NB) / 32, 256, 0, stream>>>(hist, Wdp, bd, out);
}